// Round 5
// baseline (125.030 us; speedup 1.0000x reference)
//
#include <hip/hip_runtime.h>

typedef unsigned short ushort_t;
typedef __attribute__((ext_vector_type(8))) short short8;
typedef __attribute__((ext_vector_type(4))) float floatx4;
typedef __attribute__((ext_vector_type(8))) __bf16 bf16x8;

__device__ __forceinline__ ushort_t f2b(float f) {
  union { float f; unsigned int i; } t; t.f = f;
  unsigned int u = t.i;
  return (ushort_t)((u + 0x7fffu + ((u >> 16) & 1u)) >> 16);  // RNE
}

__device__ __forceinline__ floatx4 mfma16(short8 a, short8 b, floatx4 c) {
  return __builtin_amdgcn_mfma_f32_16x16x32_bf16(
      __builtin_bit_cast(bf16x8, a), __builtin_bit_cast(bf16x8, b), c, 0, 0, 0);
}

__device__ __forceinline__ void gload16(const void* g, void* l) {
  __builtin_amdgcn_global_load_lds(
      (const __attribute__((address_space(1))) void*)g,
      (__attribute__((address_space(3))) void*)l, 16, 0, 0);
}

// ---------------------------------------------------------------------------
// f32 -> bf16 for x (4M), W_in (1M), W_out (1M). grid = 3072.
// ---------------------------------------------------------------------------
__global__ __launch_bounds__(256) void k_f2b_all(
    const float* __restrict__ x, const float* __restrict__ Wi,
    const float* __restrict__ Wo, ushort_t* __restrict__ xb,
    ushort_t* __restrict__ Wib, ushort_t* __restrict__ Wob)
{
  const float* in; ushort_t* out; int i;
  if (blockIdx.x < 2048)      { in = x;  out = xb;  i = (blockIdx.x * 256 + threadIdx.x) * 8; }
  else if (blockIdx.x < 2560) { in = Wi; out = Wib; i = ((blockIdx.x - 2048) * 256 + threadIdx.x) * 8; }
  else                        { in = Wo; out = Wob; i = ((blockIdx.x - 2560) * 256 + threadIdx.x) * 8; }
  float4 a = *reinterpret_cast<const float4*>(in + i);
  float4 b = *reinterpret_cast<const float4*>(in + i + 4);
  short8 o;
  o[0] = (short)f2b(a.x); o[1] = (short)f2b(a.y);
  o[2] = (short)f2b(a.z); o[3] = (short)f2b(a.w);
  o[4] = (short)f2b(b.x); o[5] = (short)f2b(b.y);
  o[6] = (short)f2b(b.z); o[7] = (short)f2b(b.w);
  *reinterpret_cast<short8*>(out + i) = o;
}

// ---------------------------------------------------------------------------
// Depth-2 pipelined 64x128-tile K-loop (unchanged from round 4).
// ---------------------------------------------------------------------------
__device__ __forceinline__ void gemm_loop_pipe(
    const ushort_t* __restrict__ A0, const ushort_t* __restrict__ B0, int K,
    ushort_t* sA, ushort_t* sB, floatx4 (&acc)[2][4])
{
  const int t = threadIdx.x, lane = t & 63, wave = t >> 6;
  const int wr = (wave >> 1) << 5, wc = (wave & 1) << 6;
  const int srow = t >> 2, scol = (t & 3) << 3;
  const int nk = K >> 5;

#define STAGE(kt, buf)                                                          \
  {                                                                             \
    int k0 = (kt) << 5;                                                         \
    gload16(A0 + (size_t)srow * K + k0 + scol, (char*)sA + (buf) * 4096 + t * 16); \
    gload16(B0 + (size_t)srow * K + k0 + scol, (char*)sB + (buf) * 8192 + t * 16); \
    gload16(B0 + (size_t)(64 + srow) * K + k0 + scol,                           \
            (char*)sB + (buf) * 8192 + 4096 + t * 16);                          \
  }

  STAGE(0, 0);
  STAGE(1, 1);
  for (int kt = 0; kt < nk; ++kt) {
    const int buf = kt & 3;
    if (kt + 2 < nk) {
      STAGE(kt + 2, (kt + 2) & 3);
      asm volatile("s_waitcnt vmcnt(6)" ::: "memory");
    } else if (kt + 1 < nk) {
      asm volatile("s_waitcnt vmcnt(3)" ::: "memory");
    } else {
      asm volatile("s_waitcnt vmcnt(0)" ::: "memory");
    }
    __builtin_amdgcn_s_barrier();

    const ushort_t* bA = sA + buf * 2048;
    const ushort_t* bB = sB + buf * 4096;
    short8 af[2], bf[4];
#pragma unroll
    for (int i = 0; i < 2; ++i)
      af[i] = *reinterpret_cast<const short8*>(
          &bA[(wr + i * 16 + (lane & 15)) * 32 + (lane >> 4) * 8]);
#pragma unroll
    for (int j = 0; j < 4; ++j)
      bf[j] = *reinterpret_cast<const short8*>(
          &bB[(wc + j * 16 + (lane & 15)) * 32 + (lane >> 4) * 8]);
    __builtin_amdgcn_s_setprio(1);
#pragma unroll
    for (int i = 0; i < 2; ++i)
#pragma unroll
      for (int j = 0; j < 4; ++j)
        acc[i][j] = mfma16(af[i], bf[j], acc[i][j]);
    __builtin_amdgcn_s_setprio(0);
  }
#undef STAGE
}

// ---------------------------------------------------------------------------
// GEMM 1: Yt[h*256 + b*64 + d][s] = sum_k W_in[h*64+d][k] * x[b*1024+s][k]
// ---------------------------------------------------------------------------
__global__ __launch_bounds__(256) void k_gemm_xw(
    const ushort_t* __restrict__ W, const ushort_t* __restrict__ X,
    ushort_t* __restrict__ Yt)
{
  __shared__ ushort_t sA[4 * 64 * 32];
  __shared__ ushort_t sB[4 * 128 * 32];
  const int m0 = (blockIdx.x & 15) << 6, n0 = (blockIdx.x >> 4) << 7;
  floatx4 acc[2][4] = {};
  gemm_loop_pipe(W + (size_t)m0 * 1024, X + (size_t)n0 * 1024, 1024, sA, sB, acc);

  const int lane = threadIdx.x & 63, wave = threadIdx.x >> 6;
  const int wr = (wave >> 1) << 5, wc = (wave & 1) << 6;
  const int c16 = lane & 15, rg = lane >> 4;
#pragma unroll
  for (int i = 0; i < 2; ++i)
#pragma unroll
    for (int j = 0; j < 4; ++j)
#pragma unroll
      for (int r = 0; r < 4; ++r) {
        int wrow = m0 + wr + i * 16 + rg * 4 + r;   // = h*64 + d
        int col  = n0 + wc + j * 16 + c16;          // = b*1024 + s
        int h = wrow >> 6, d = wrow & 63;
        int b = col >> 10, s = col & 1023;
        Yt[(((size_t)(h * 4 + b) << 6) + d) * 1024 + s] = f2b(acc[i][j][r]);
      }
}

// ---------------------------------------------------------------------------
// FUSED: softmax stats + R-tile + PV GEMM. One block per (h, 64-row m-tile).
// grid = 256 (h-chunked across XCDs), 512 threads = 8 waves (2m x 4n; the
// 4 n-waves each own one batch b).
// Phase A: stream attn[h, m0:m0+64, :] f32, per-row online stats -> rowm/
//   rowinv, 17 bucket weights, Rtile[64][64] = wmid @ relv.
// Phase B: K-loop (BK=64, 16 steps): A-frags = exp(attn - m)*inv on the fly
//   (L1-hot re-read); B = Yt staged to LDS via gload16 with chunk-XOR
//   swizzle (source-side) matching the XOR on ds_read (rule #21).
//   Loop: [vmcnt(0); s_barrier; stage(kt+1); compute(kt)] - race-free dbuf.
// ---------------------------------------------------------------------------
__global__ __launch_bounds__(512) void k_fused_pv(
    const float* __restrict__ attn, const float* __restrict__ relv,
    const ushort_t* __restrict__ Yt, ushort_t* __restrict__ O)
{
  __shared__ ushort_t sY[2][16384];      // 2 x 32KB: chunk c=row*8+cb, 16B each
  __shared__ float Rtile[64][64];        // 16KB
  __shared__ float pmax[64][8], psum[64][8], psA[64][8], psB[64][8];
  __shared__ float vmid[64][15];         // raw mid-bucket scores
  __shared__ float wmid[64][17];         // normalized bucket weights
  __shared__ float rowm[64], rowinv[64];
  __shared__ float srelv[17 * 64];

  const int t = threadIdx.x;
  const int bid = blockIdx.x;
  const int loc = bid >> 3;
  const int h = ((bid & 7) << 1) + (loc >> 4);   // 2 heads per XCD (perf-only)
  const int mt = loc & 15;
  const int m0 = mt << 6;
  const float* Ah = attn + ((size_t)h << 20) + ((size_t)m0 << 10);
  const ushort_t* Yh = Yt + (((size_t)h << 8) << 10);   // h*256*1024

#define STAGEY(kt, buf)                                                   \
  {                                                                       \
    const int k0y = (kt) << 6;                                            \
    _Pragma("unroll")                                                     \
    for (int cc = 0; cc < 4; ++cc) {                                      \
      int c = t + cc * 512;                                               \
      int row = c >> 3, cb = c & 7;                                       \
      gload16(Yh + (size_t)row * 1024 + k0y + ((cb ^ (row & 7)) << 3),    \
              (char*)&sY[buf][0] + c * 16);                               \
    }                                                                     \
  }

  // issue K-tile 0 staging first: latency hides under all of phase A
  STAGEY(0, 0);

  // ---- phase A ----
  for (int i = t; i < 64 * 15; i += 512) ((float*)vmid)[i] = -3e38f;
  for (int i = t; i < 17 * 64; i += 512) srelv[i] = relv[i];
  __syncthreads();

  const int r = t >> 3, q = t & 7;
  const int s_glob = m0 + r;
  const float* rowp = Ah + ((size_t)r << 10) + (q << 7);

  float lm = -3e38f;
  for (int c = 0; c < 32; ++c) {
    float4 v = reinterpret_cast<const float4*>(rowp)[c];
    lm = fmaxf(fmaxf(fmaxf(lm, v.x), v.y), fmaxf(v.z, v.w));
  }
  float ls = 0.f, la = 0.f, lb = 0.f;
  for (int c = 0; c < 32; ++c) {
    float4 v = reinterpret_cast<const float4*>(rowp)[c];
#pragma unroll
    for (int e = 0; e < 4; ++e) {
      float ve = (e == 0) ? v.x : (e == 1) ? v.y : (e == 2) ? v.z : v.w;
      int j = (q << 7) + c * 4 + e;
      float pe = __expf(ve - lm);
      ls += pe;
      la += (j <= s_glob - 8) ? pe : 0.f;
      lb += (j >= s_glob + 8) ? pe : 0.f;
      unsigned tt = (unsigned)(j - (s_glob - 7));
      if (tt < 15u) vmid[r][tt] = ve;
    }
  }
  pmax[r][q] = lm; psum[r][q] = ls; psA[r][q] = la; psB[r][q] = lb;
  __syncthreads();

  if (t < 64) {
    float m = pmax[t][0];
#pragma unroll
    for (int qq = 1; qq < 8; ++qq) m = fmaxf(m, pmax[t][qq]);
    float tot = 0.f, sa = 0.f, sb = 0.f;
#pragma unroll
    for (int qq = 0; qq < 8; ++qq) {
      float e = __expf(pmax[t][qq] - m);
      tot += psum[t][qq] * e; sa += psA[t][qq] * e; sb += psB[t][qq] * e;
    }
    float inv = 1.0f / tot;
    rowm[t] = m; rowinv[t] = inv;
    wmid[t][0] = sa * inv; wmid[t][16] = sb * inv;
#pragma unroll
    for (int tt = 0; tt < 15; ++tt)
      wmid[t][1 + tt] = __expf(vmid[t][tt] - m) * inv;
  }
  __syncthreads();

  {
    const int rr = t >> 3, d0 = (t & 7) << 3;
#pragma unroll
    for (int dd = 0; dd < 8; ++dd) {
      float a = 0.f;
#pragma unroll
      for (int k = 0; k < 17; ++k) a += wmid[rr][k] * srelv[k * 64 + d0 + dd];
      Rtile[rr][d0 + dd] = a;
    }
  }

  // ---- phase B ----
  const int lane = t & 63, wave = t >> 6;
  const int wr = (wave >> 2) << 5;          // 0 | 32
  const int wc = (wave & 3) << 6;           // b = wave&3
  const int l15 = lane & 15, lk = lane >> 4;

  const float rm0 = rowm[wr + l15],      ri0 = rowinv[wr + l15];
  const float rm1 = rowm[wr + 16 + l15], ri1 = rowinv[wr + 16 + l15];
  const float* afb0 = Ah + ((size_t)(wr + l15) << 10) + (lk << 3);
  const float* afb1 = afb0 + (16 << 10);

  floatx4 acc[2][4] = {};

  for (int kt = 0; kt < 16; ++kt) {
    asm volatile("s_waitcnt vmcnt(0)" ::: "memory");
    __builtin_amdgcn_s_barrier();
    if (kt + 1 < 16) STAGEY(kt + 1, (kt + 1) & 1);
    const char* buf = (const char*)&sY[kt & 1][0];

#pragma unroll
    for (int half = 0; half < 2; ++half) {
      const int kk = (kt << 6) + (half << 5);
      float4 va0 = *reinterpret_cast<const float4*>(afb0 + kk);
      float4 vb0 = *reinterpret_cast<const float4*>(afb0 + kk + 4);
      float4 va1 = *reinterpret_cast<const float4*>(afb1 + kk);
      float4 vb1 = *reinterpret_cast<const float4*>(afb1 + kk + 4);
      short8 af0, af1;
      af0[0] = (short)f2b(__expf(va0.x - rm0) * ri0);
      af0[1] = (short)f2b(__expf(va0.y - rm0) * ri0);
      af0[2] = (short)f2b(__expf(va0.z - rm0) * ri0);
      af0[3] = (short)f2b(__expf(va0.w - rm0) * ri0);
      af0[4] = (short)f2b(__expf(vb0.x - rm0) * ri0);
      af0[5] = (short)f2b(__expf(vb0.y - rm0) * ri0);
      af0[6] = (short)f2b(__expf(vb0.z - rm0) * ri0);
      af0[7] = (short)f2b(__expf(vb0.w - rm0) * ri0);
      af1[0] = (short)f2b(__expf(va1.x - rm1) * ri1);
      af1[1] = (short)f2b(__expf(va1.y - rm1) * ri1);
      af1[2] = (short)f2b(__expf(va1.z - rm1) * ri1);
      af1[3] = (short)f2b(__expf(va1.w - rm1) * ri1);
      af1[4] = (short)f2b(__expf(vb1.x - rm1) * ri1);
      af1[5] = (short)f2b(__expf(vb1.y - rm1) * ri1);
      af1[6] = (short)f2b(__expf(vb1.z - rm1) * ri1);
      af1[7] = (short)f2b(__expf(vb1.w - rm1) * ri1);

      const int cs = (half << 2) + lk;
      short8 bf[4];
#pragma unroll
      for (int j = 0; j < 4; ++j) {
        int nr = wc + (j << 4) + l15;
        bf[j] = *reinterpret_cast<const short8*>(
            buf + nr * 128 + ((cs ^ (nr & 7)) << 4));
      }
      __builtin_amdgcn_s_setprio(1);
#pragma unroll
      for (int j = 0; j < 4; ++j) {
        acc[0][j] = mfma16(af0, bf[j], acc[0][j]);
        acc[1][j] = mfma16(af1, bf[j], acc[1][j]);
      }
      __builtin_amdgcn_s_setprio(0);
    }
  }
#undef STAGEY

  // ---- epilogue: + Rtile, write O ----
  const int b = wave & 3;
#pragma unroll
  for (int i = 0; i < 2; ++i)
#pragma unroll
    for (int j = 0; j < 4; ++j) {
      int d = (j << 4) + l15;
#pragma unroll
      for (int rr = 0; rr < 4; ++rr) {
        int srl = wr + (i << 4) + (lk << 2) + rr;
        float val = acc[i][j][rr] + Rtile[srl][d];
        O[((size_t)b << 20) + ((size_t)(m0 + srl) << 10) + (h << 6) + d] = f2b(val);
      }
    }
}

// ---------------------------------------------------------------------------
// GEMM 3: out[m][n] = sum_k O[m][k] * W_out[n][k]  (f32 out). grid = 512.
// ---------------------------------------------------------------------------
__global__ __launch_bounds__(256) void k_gemm_out(
    const ushort_t* __restrict__ A, const ushort_t* __restrict__ B,
    float* __restrict__ C)
{
  __shared__ ushort_t sA[4 * 64 * 32];
  __shared__ ushort_t sB[4 * 128 * 32];
  const int m0 = (blockIdx.x >> 3) << 6, n0 = (blockIdx.x & 7) << 7;
  floatx4 acc[2][4] = {};
  gemm_loop_pipe(A + (size_t)m0 * 1024, B + (size_t)n0 * 1024, 1024, sA, sB, acc);

  const int lane = threadIdx.x & 63, wave = threadIdx.x >> 6;
  const int wr = (wave >> 1) << 5, wc = (wave & 1) << 6;
  const int c16 = lane & 15, rg = lane >> 4;
#pragma unroll
  for (int i = 0; i < 2; ++i)
#pragma unroll
    for (int j = 0; j < 4; ++j)
#pragma unroll
      for (int r = 0; r < 4; ++r) {
        int rowg = m0 + wr + i * 16 + rg * 4 + r;
        int colg = n0 + wc + j * 16 + c16;
        C[(size_t)rowg * 1024 + colg] = acc[i][j][r];
      }
}

// ---------------------------------------------------------------------------
extern "C" void kernel_launch(void* const* d_in, const int* in_sizes, int n_in,
                              void* d_out, int out_size, void* d_ws, size_t ws_size,
                              hipStream_t stream)
{
  const float* x     = (const float*)d_in[0];
  const float* W_in  = (const float*)d_in[1];
  const float* W_out = (const float*)d_in[2];
  const float* attn  = (const float*)d_in[3];
  const float* relv  = (const float*)d_in[4];
  float* out = (float*)d_out;

  char* ws = (char*)d_ws;
  ushort_t* xb  = (ushort_t*)(ws);                //  8 MB
  ushort_t* Wib = (ushort_t*)(ws + (8u << 20));   //  2 MB
  ushort_t* Wob = (ushort_t*)(ws + (10u << 20));  //  2 MB
  ushort_t* Yt  = (ushort_t*)(ws + (12u << 20));  //  8 MB  [h*256 + b*64 + d][s]
  ushort_t* O   = (ushort_t*)(ws + (20u << 20));  //  8 MB  [b][s][h*64+d]

  k_f2b_all<<<3072, 256, 0, stream>>>(x, W_in, W_out, xb, Wib, Wob);
  k_gemm_xw<<<512, 256, 0, stream>>>(Wib, xb, Yt);
  k_fused_pv<<<256, 512, 0, stream>>>(attn, relv, Yt, O);
  k_gemm_out<<<512, 256, 0, stream>>>(O, Wob, out);
}

// Round 6
// 103.990 us; speedup vs baseline: 1.2023x; 1.2023x over previous
//
#include <hip/hip_runtime.h>

typedef unsigned short ushort_t;
typedef __attribute__((ext_vector_type(8))) short short8;
typedef __attribute__((ext_vector_type(4))) float floatx4;
typedef __attribute__((ext_vector_type(8))) __bf16 bf16x8;

__device__ __forceinline__ ushort_t f2b(float f) {
  union { float f; unsigned int i; } t; t.f = f;
  unsigned int u = t.i;
  return (ushort_t)((u + 0x7fffu + ((u >> 16) & 1u)) >> 16);  // RNE
}

__device__ __forceinline__ floatx4 mfma16(short8 a, short8 b, floatx4 c) {
  return __builtin_amdgcn_mfma_f32_16x16x32_bf16(
      __builtin_bit_cast(bf16x8, a), __builtin_bit_cast(bf16x8, b), c, 0, 0, 0);
}

__device__ __forceinline__ void gload16(const void* g, void* l) {
  __builtin_amdgcn_global_load_lds(
      (const __attribute__((address_space(1))) void*)g,
      (__attribute__((address_space(3))) void*)l, 16, 0, 0);
}

// ---------------------------------------------------------------------------
// f32 -> bf16 for x (4M), W_in (1M), W_out (1M). grid = 3072.
// ---------------------------------------------------------------------------
__global__ __launch_bounds__(256) void k_f2b_all(
    const float* __restrict__ x, const float* __restrict__ Wi,
    const float* __restrict__ Wo, ushort_t* __restrict__ xb,
    ushort_t* __restrict__ Wib, ushort_t* __restrict__ Wob)
{
  const float* in; ushort_t* out; int i;
  if (blockIdx.x < 2048)      { in = x;  out = xb;  i = (blockIdx.x * 256 + threadIdx.x) * 8; }
  else if (blockIdx.x < 2560) { in = Wi; out = Wib; i = ((blockIdx.x - 2048) * 256 + threadIdx.x) * 8; }
  else                        { in = Wo; out = Wob; i = ((blockIdx.x - 2560) * 256 + threadIdx.x) * 8; }
  float4 a = *reinterpret_cast<const float4*>(in + i);
  float4 b = *reinterpret_cast<const float4*>(in + i + 4);
  short8 o;
  o[0] = (short)f2b(a.x); o[1] = (short)f2b(a.y);
  o[2] = (short)f2b(a.z); o[3] = (short)f2b(a.w);
  o[4] = (short)f2b(b.x); o[5] = (short)f2b(b.y);
  o[6] = (short)f2b(b.z); o[7] = (short)f2b(b.w);
  *reinterpret_cast<short8*>(out + i) = o;
}

// ---------------------------------------------------------------------------
// Depth-2 pipelined 64x128-tile K-loop (verified, round 4).
// ---------------------------------------------------------------------------
__device__ __forceinline__ void gemm_loop_pipe(
    const ushort_t* __restrict__ A0, const ushort_t* __restrict__ B0, int K,
    ushort_t* sA, ushort_t* sB, floatx4 (&acc)[2][4])
{
  const int t = threadIdx.x, lane = t & 63, wave = t >> 6;
  const int wr = (wave >> 1) << 5, wc = (wave & 1) << 6;
  const int srow = t >> 2, scol = (t & 3) << 3;
  const int nk = K >> 5;

#define STAGE(kt, buf)                                                          \
  {                                                                             \
    int k0 = (kt) << 5;                                                         \
    gload16(A0 + (size_t)srow * K + k0 + scol, (char*)sA + (buf) * 4096 + t * 16); \
    gload16(B0 + (size_t)srow * K + k0 + scol, (char*)sB + (buf) * 8192 + t * 16); \
    gload16(B0 + (size_t)(64 + srow) * K + k0 + scol,                           \
            (char*)sB + (buf) * 8192 + 4096 + t * 16);                          \
  }

  STAGE(0, 0);
  STAGE(1, 1);
  for (int kt = 0; kt < nk; ++kt) {
    const int buf = kt & 3;
    if (kt + 2 < nk) {
      STAGE(kt + 2, (kt + 2) & 3);
      asm volatile("s_waitcnt vmcnt(6)" ::: "memory");
    } else if (kt + 1 < nk) {
      asm volatile("s_waitcnt vmcnt(3)" ::: "memory");
    } else {
      asm volatile("s_waitcnt vmcnt(0)" ::: "memory");
    }
    __builtin_amdgcn_s_barrier();

    const ushort_t* bA = sA + buf * 2048;
    const ushort_t* bB = sB + buf * 4096;
    short8 af[2], bf[4];
#pragma unroll
    for (int i = 0; i < 2; ++i)
      af[i] = *reinterpret_cast<const short8*>(
          &bA[(wr + i * 16 + (lane & 15)) * 32 + (lane >> 4) * 8]);
#pragma unroll
    for (int j = 0; j < 4; ++j)
      bf[j] = *reinterpret_cast<const short8*>(
          &bB[(wc + j * 16 + (lane & 15)) * 32 + (lane >> 4) * 8]);
    __builtin_amdgcn_s_setprio(1);
#pragma unroll
    for (int i = 0; i < 2; ++i)
#pragma unroll
      for (int j = 0; j < 4; ++j)
        acc[i][j] = mfma16(af[i], bf[j], acc[i][j]);
    __builtin_amdgcn_s_setprio(0);
  }
#undef STAGE
}

// ---------------------------------------------------------------------------
// GEMM 1: Yt[h*256 + b*64 + d][s] = sum_k W_in[h*64+d][k] * x[b*1024+s][k]
// ---------------------------------------------------------------------------
__global__ __launch_bounds__(256) void k_gemm_xw(
    const ushort_t* __restrict__ W, const ushort_t* __restrict__ X,
    ushort_t* __restrict__ Yt)
{
  __shared__ ushort_t sA[4 * 64 * 32];
  __shared__ ushort_t sB[4 * 128 * 32];
  const int m0 = (blockIdx.x & 15) << 6, n0 = (blockIdx.x >> 4) << 7;
  floatx4 acc[2][4] = {};
  gemm_loop_pipe(W + (size_t)m0 * 1024, X + (size_t)n0 * 1024, 1024, sA, sB, acc);

  const int lane = threadIdx.x & 63, wave = threadIdx.x >> 6;
  const int wr = (wave >> 1) << 5, wc = (wave & 1) << 6;
  const int c16 = lane & 15, rg = lane >> 4;
#pragma unroll
  for (int i = 0; i < 2; ++i)
#pragma unroll
    for (int j = 0; j < 4; ++j)
#pragma unroll
      for (int r = 0; r < 4; ++r) {
        int wrow = m0 + wr + i * 16 + rg * 4 + r;   // = h*64 + d
        int col  = n0 + wc + j * 16 + c16;          // = b*1024 + s
        int h = wrow >> 6, d = wrow & 63;
        int b = col >> 10, s = col & 1023;
        Yt[(((size_t)(h * 4 + b) << 6) + d) * 1024 + s] = f2b(acc[i][j][r]);
      }
}

// ---------------------------------------------------------------------------
// FLASH PV: one block per (h, 64-row tile). grid = 256 (h = bid&15 -> XCD
// co-locates each head pair's 1MB Yt in L2). 512 thr = 8 waves (4m x 2n).
// Online softmax over 4 K-chunks of 256: pass1 coalesced row-max ->
// rescale acc; pass2 (L1/L2-hot re-read) exp -> bf16 A-frags af[8] in regs,
// unnormalized; kt-loop: Yt from LDS (depth-2 counted-vmcnt pipeline,
// XOR-swizzled src + matching read). Epilogue: *1/rowtot, + R-tile, write O.
// ---------------------------------------------------------------------------
__global__ __launch_bounds__(512) void k_flash_pv(
    const float* __restrict__ attn, const float* __restrict__ relv,
    const ushort_t* __restrict__ Yt, ushort_t* __restrict__ O)
{
  __shared__ ushort_t sY[4][8192];               // 4 x 16KB (256 rows x 32 k)
  __shared__ float Rtile[64][64];                // 16KB
  __shared__ __align__(16) float rowm[64], rowscale[64], rowtot[64];
  __shared__ __align__(16) float rowsA[64], rowsB[64], rowinv[64];
  __shared__ float vmid[64][15];
  __shared__ float wmid[64][17];
  __shared__ float srelv[17 * 64];

  const int t = threadIdx.x;
  const int h = blockIdx.x & 15, mt = blockIdx.x >> 4;
  const int m0 = mt << 6;
  const float* Ah = attn + ((size_t)h << 20) + ((size_t)m0 << 10);
  const ushort_t* Yh = Yt + ((size_t)h << 18);   // h*256*1024

  const int lane = t & 63, wave = t >> 6;
  const int mw = wave & 3, nw = wave >> 2;
  const int wr = mw << 4;                        // 16-row band
  const int l15 = lane & 15, lk = lane >> 4;

  // stage Yt k-slice kt (256 rows x 32 cols, 16KB) into sY[buf].
  // chunk c (16B): row=c>>2, cb=c&3; linear LDS dest (t*16 per wave-lane),
  // source pre-swizzled cb^(row&3) to match the read-side XOR (rule 21).
#define STAGEY(kt, buf)                                                     \
  {                                                                         \
    int c1 = t, c2 = 512 + t;                                               \
    int r1 = c1 >> 2, cb1 = c1 & 3;                                         \
    int r2 = c2 >> 2, cb2 = c2 & 3;                                         \
    gload16(Yh + (size_t)r1 * 1024 + ((kt) << 5) + ((cb1 ^ (r1 & 3)) << 3), \
            (char*)&sY[buf][0] + c1 * 16);                                  \
    gload16(Yh + (size_t)r2 * 1024 + ((kt) << 5) + ((cb2 ^ (r2 & 3)) << 3), \
            (char*)&sY[buf][0] + c2 * 16);                                  \
  }

  STAGEY(0, 0);
  STAGEY(1, 1);

  if (t < 64) { rowm[t] = -3e38f; rowtot[t] = 0.f; rowsA[t] = 0.f; rowsB[t] = 0.f; }
  for (int i = t; i < 64 * 15; i += 512) ((float*)vmid)[i] = -3e38f;
  for (int i = t; i < 17 * 64; i += 512) srelv[i] = relv[i];
  __syncthreads();

  floatx4 acc[8] = {};
  const int s_row = m0 + wr + l15;               // global s of this lane's A row
  int ktg = 0;

  for (int ch = 0; ch < 4; ++ch) {
    const int j0 = ch << 8;
    const float* rp = Ah + ((size_t)(wr + l15) << 10) + j0 + (lk << 3);

    // ---- pass 1: chunk row-max (coalesced: 16 rows x 128B per wave) ----
    float cm = -3e38f;
#pragma unroll
    for (int k8 = 0; k8 < 8; ++k8) {
      float4 a = *reinterpret_cast<const float4*>(rp + (k8 << 5));
      float4 b = *reinterpret_cast<const float4*>(rp + (k8 << 5) + 4);
      cm = fmaxf(cm, fmaxf(fmaxf(a.x, a.y), fmaxf(a.z, a.w)));
      cm = fmaxf(cm, fmaxf(fmaxf(b.x, b.y), fmaxf(b.z, b.w)));
    }
    cm = fmaxf(cm, __shfl_xor(cm, 16));
    cm = fmaxf(cm, __shfl_xor(cm, 32));
    if (nw == 0 && lk == 0) {
      int r = wr + l15;
      float mo = rowm[r], mn = fmaxf(mo, cm);
      rowm[r] = mn; rowscale[r] = __expf(mo - mn);
    }
    __syncthreads();

    // ---- rescale acc by exp(m_old - m_new) of each element's row ----
    {
      floatx4 sc = *reinterpret_cast<const floatx4*>(&rowscale[wr + (lk << 2)]);
#pragma unroll
      for (int j = 0; j < 8; ++j)
#pragma unroll
        for (int rr = 0; rr < 4; ++rr) acc[j][rr] *= sc[rr];
    }

    // ---- pass 2: exp -> bf16 A-frags for the whole chunk (L1/L2-hot) ----
    const float rm = rowm[wr + l15];
    short8 af[8];
    float pt = 0.f, pa = 0.f, pb = 0.f;
#pragma unroll
    for (int k8 = 0; k8 < 8; ++k8) {
      float4 a = *reinterpret_cast<const float4*>(rp + (k8 << 5));
      float4 b = *reinterpret_cast<const float4*>(rp + (k8 << 5) + 4);
      float vs[8] = {a.x, a.y, a.z, a.w, b.x, b.y, b.z, b.w};
      float es[8];
      short8 f;
#pragma unroll
      for (int e = 0; e < 8; ++e) {
        es[e] = __expf(vs[e] - rm);
        f[e] = (short)f2b(es[e]);
      }
      af[k8] = f;
      if (nw == 0) {
        int jb = j0 + (k8 << 5) + (lk << 3);
#pragma unroll
        for (int e = 0; e < 8; ++e) {
          int j = jb + e;
          pt += es[e];
          pa += (j <= s_row - 8) ? es[e] : 0.f;
          pb += (j >= s_row + 8) ? es[e] : 0.f;
          unsigned tt = (unsigned)(j - (s_row - 7));
          if (tt < 15u) vmid[wr + l15][tt] = vs[e];
        }
      }
    }
    if (nw == 0) {
      pt += __shfl_xor(pt, 16); pa += __shfl_xor(pa, 16); pb += __shfl_xor(pb, 16);
      pt += __shfl_xor(pt, 32); pa += __shfl_xor(pa, 32); pb += __shfl_xor(pb, 32);
      if (lk == 0) {
        int r = wr + l15; float sc = rowscale[r];
        rowtot[r] = rowtot[r] * sc + pt;
        rowsA[r]  = rowsA[r]  * sc + pa;
        rowsB[r]  = rowsB[r]  * sc + pb;
      }
    }

    // ---- kt loop: 8 x BK=32, pipelined Yt staging ----
#pragma unroll
    for (int kq = 0; kq < 8; ++kq, ++ktg) {
      if (ktg + 2 < 32) {
        STAGEY(ktg + 2, (ktg + 2) & 3);
        asm volatile("s_waitcnt vmcnt(4)" ::: "memory");
      } else if (ktg + 1 < 32) {
        asm volatile("s_waitcnt vmcnt(2)" ::: "memory");
      } else {
        asm volatile("s_waitcnt vmcnt(0)" ::: "memory");
      }
      __builtin_amdgcn_s_barrier();
      const char* buf = (const char*)&sY[ktg & 3][0];
      short8 bf[8];
#pragma unroll
      for (int j = 0; j < 8; ++j) {
        int nr = (nw << 7) + (j << 4) + l15;
        bf[j] = *reinterpret_cast<const short8*>(
            buf + nr * 64 + ((lk ^ (nr & 3)) << 4));
      }
      __builtin_amdgcn_s_setprio(1);
#pragma unroll
      for (int j = 0; j < 8; ++j) acc[j] = mfma16(af[kq], bf[j], acc[j]);
      __builtin_amdgcn_s_setprio(0);
    }
  }
#undef STAGEY

  // ---- epilogue ----
  __syncthreads();
  if (t < 64) {
    float inv = 1.0f / rowtot[t];
    rowinv[t] = inv;
    float m = rowm[t];
    wmid[t][0] = rowsA[t] * inv;
    wmid[t][16] = rowsB[t] * inv;
#pragma unroll
    for (int tt = 0; tt < 15; ++tt)
      wmid[t][1 + tt] = __expf(vmid[t][tt] - m) * inv;
  }
  __syncthreads();
  {
    const int rr = t >> 3, d0 = (t & 7) << 3;
#pragma unroll
    for (int dd = 0; dd < 8; ++dd) {
      float a = 0.f;
#pragma unroll
      for (int k = 0; k < 17; ++k) a += wmid[rr][k] * srelv[k * 64 + d0 + dd];
      Rtile[rr][d0 + dd] = a;
    }
  }
  __syncthreads();

  floatx4 riv = *reinterpret_cast<const floatx4*>(&rowinv[wr + (lk << 2)]);
#pragma unroll
  for (int j = 0; j < 8; ++j) {
    int n = (nw << 7) + (j << 4) + l15;
    int b = n >> 6, d = n & 63;
#pragma unroll
    for (int rr = 0; rr < 4; ++rr) {
      int rl = wr + (lk << 2) + rr;
      float val = acc[j][rr] * riv[rr] + Rtile[rl][d];
      O[((size_t)b << 20) + ((size_t)(m0 + rl) << 10) + (h << 6) + d] = f2b(val);
    }
  }
}

// ---------------------------------------------------------------------------
// GEMM 3: out[m][n] = sum_k O[m][k] * W_out[n][k]  (f32 out). grid = 512.
// ---------------------------------------------------------------------------
__global__ __launch_bounds__(256) void k_gemm_out(
    const ushort_t* __restrict__ A, const ushort_t* __restrict__ B,
    float* __restrict__ C)
{
  __shared__ ushort_t sA[4 * 64 * 32];
  __shared__ ushort_t sB[4 * 128 * 32];
  const int m0 = (blockIdx.x >> 3) << 6, n0 = (blockIdx.x & 7) << 7;
  floatx4 acc[2][4] = {};
  gemm_loop_pipe(A + (size_t)m0 * 1024, B + (size_t)n0 * 1024, 1024, sA, sB, acc);

  const int lane = threadIdx.x & 63, wave = threadIdx.x >> 6;
  const int wr = (wave >> 1) << 5, wc = (wave & 1) << 6;
  const int c16 = lane & 15, rg = lane >> 4;
#pragma unroll
  for (int i = 0; i < 2; ++i)
#pragma unroll
    for (int j = 0; j < 4; ++j)
#pragma unroll
      for (int r = 0; r < 4; ++r) {
        int rowg = m0 + wr + i * 16 + rg * 4 + r;
        int colg = n0 + wc + j * 16 + c16;
        C[(size_t)rowg * 1024 + colg] = acc[i][j][r];
      }
}

// ---------------------------------------------------------------------------
extern "C" void kernel_launch(void* const* d_in, const int* in_sizes, int n_in,
                              void* d_out, int out_size, void* d_ws, size_t ws_size,
                              hipStream_t stream)
{
  const float* x     = (const float*)d_in[0];
  const float* W_in  = (const float*)d_in[1];
  const float* W_out = (const float*)d_in[2];
  const float* attn  = (const float*)d_in[3];
  const float* relv  = (const float*)d_in[4];
  float* out = (float*)d_out;

  char* ws = (char*)d_ws;
  ushort_t* xb  = (ushort_t*)(ws);                //  8 MB
  ushort_t* Wib = (ushort_t*)(ws + (8u << 20));   //  2 MB
  ushort_t* Wob = (ushort_t*)(ws + (10u << 20));  //  2 MB
  ushort_t* Yt  = (ushort_t*)(ws + (12u << 20));  //  8 MB  [h*256 + b*64 + d][s]
  ushort_t* O   = (ushort_t*)(ws + (20u << 20));  //  8 MB  [b][s][h*64+d]

  k_f2b_all<<<3072, 256, 0, stream>>>(x, W_in, W_out, xb, Wib, Wob);
  k_gemm_xw<<<512, 256, 0, stream>>>(Wib, xb, Yt);
  k_flash_pv<<<256, 512, 0, stream>>>(attn, relv, Yt, O);
  k_gemm_out<<<512, 256, 0, stream>>>(O, Wob, out);
}

// Round 7
// 66.918 us; speedup vs baseline: 1.8684x; 1.5540x over previous
//
#include <hip/hip_runtime.h>

typedef unsigned short ushort_t;
typedef __attribute__((ext_vector_type(4))) short short4_t;
typedef __attribute__((ext_vector_type(8))) short short8;
typedef __attribute__((ext_vector_type(4))) float floatx4;
typedef __attribute__((ext_vector_type(8))) __bf16 bf16x8;

__device__ __forceinline__ ushort_t f2b(float f) {
  union { float f; unsigned int i; } t; t.f = f;
  unsigned int u = t.i;
  return (ushort_t)((u + 0x7fffu + ((u >> 16) & 1u)) >> 16);  // RNE
}

__device__ __forceinline__ floatx4 mfma16(short8 a, short8 b, floatx4 c) {
  return __builtin_amdgcn_mfma_f32_16x16x32_bf16(
      __builtin_bit_cast(bf16x8, a), __builtin_bit_cast(bf16x8, b), c, 0, 0, 0);
}

__device__ __forceinline__ void gload16(const void* g, void* l) {
  __builtin_amdgcn_global_load_lds(
      (const __attribute__((address_space(1))) void*)g,
      (__attribute__((address_space(3))) void*)l, 16, 0, 0);
}

// ---------------------------------------------------------------------------
// f32 -> bf16 for x (4M), W_in (1M), W_out (1M). grid = 3072.
// ---------------------------------------------------------------------------
__global__ __launch_bounds__(256) void k_f2b_all(
    const float* __restrict__ x, const float* __restrict__ Wi,
    const float* __restrict__ Wo, ushort_t* __restrict__ xb,
    ushort_t* __restrict__ Wib, ushort_t* __restrict__ Wob)
{
  const float* in; ushort_t* out; int i;
  if (blockIdx.x < 2048)      { in = x;  out = xb;  i = (blockIdx.x * 256 + threadIdx.x) * 8; }
  else if (blockIdx.x < 2560) { in = Wi; out = Wib; i = ((blockIdx.x - 2048) * 256 + threadIdx.x) * 8; }
  else                        { in = Wo; out = Wob; i = ((blockIdx.x - 2560) * 256 + threadIdx.x) * 8; }
  float4 a = *reinterpret_cast<const float4*>(in + i);
  float4 b = *reinterpret_cast<const float4*>(in + i + 4);
  short8 o;
  o[0] = (short)f2b(a.x); o[1] = (short)f2b(a.y);
  o[2] = (short)f2b(a.z); o[3] = (short)f2b(a.w);
  o[4] = (short)f2b(b.x); o[5] = (short)f2b(b.y);
  o[6] = (short)f2b(b.z); o[7] = (short)f2b(b.w);
  *reinterpret_cast<short8*>(out + i) = o;
}

// ---------------------------------------------------------------------------
// P = softmax(attn_scores[0]) (bf16), R[h,s,:] = rel-bucket mix (f32).
// One wave per (h,s) row. 4 waves/block. grid = 4096.  (verified round 2-4)
// ---------------------------------------------------------------------------
__global__ __launch_bounds__(256) void k_softmax_rel(
    const float* __restrict__ S, const float* __restrict__ relv,
    ushort_t* __restrict__ P, float* __restrict__ R)
{
  __shared__ float mid[4][16];
  const int wave = threadIdx.x >> 6, lane = threadIdx.x & 63;
  const int row = blockIdx.x * 4 + wave;   // h*1024 + s
  const int s = row & 1023;
  const float* src = S + (size_t)row * 1024;

  float v[4][4];
#pragma unroll
  for (int c = 0; c < 4; ++c) {
    float4 raw = *reinterpret_cast<const float4*>(src + c * 256 + lane * 4);
    v[c][0] = raw.x; v[c][1] = raw.y; v[c][2] = raw.z; v[c][3] = raw.w;
  }
  float m = -1e30f;
#pragma unroll
  for (int c = 0; c < 4; ++c)
#pragma unroll
    for (int e = 0; e < 4; ++e) m = fmaxf(m, v[c][e]);
#pragma unroll
  for (int d = 32; d; d >>= 1) m = fmaxf(m, __shfl_xor(m, d));

  float p[4][4];
  float tot = 0.f, sA = 0.f, sB = 0.f;
#pragma unroll
  for (int c = 0; c < 4; ++c) {
#pragma unroll
    for (int e = 0; e < 4; ++e) {
      int j = c * 256 + lane * 4 + e;
      float pe = __expf(v[c][e] - m);
      p[c][e] = pe;
      tot += pe;
      sA += (j <= s - 8) ? pe : 0.f;
      sB += (j >= s + 8) ? pe : 0.f;
    }
  }
#pragma unroll
  for (int d = 32; d; d >>= 1) {
    tot += __shfl_xor(tot, d);
    sA  += __shfl_xor(sA, d);
    sB  += __shfl_xor(sB, d);
  }
  const float inv = 1.0f / tot;

  if (lane < 16) mid[wave][lane] = 0.f;
  __syncthreads();
#pragma unroll
  for (int c = 0; c < 4; ++c) {
#pragma unroll
    for (int e = 0; e < 4; ++e) {
      int j = c * 256 + lane * 4 + e;
      int tt = j - (s - 7);
      if (tt >= 0 && tt < 15) mid[wave][tt] = p[c][e];
    }
  }
  __syncthreads();

  float acc = sA * relv[lane] + sB * relv[16 * 64 + lane];
#pragma unroll
  for (int tt = 0; tt < 15; ++tt)
    acc += mid[wave][tt] * relv[(1 + tt) * 64 + lane];
  R[(size_t)row * 64 + lane] = acc * inv;

#pragma unroll
  for (int c = 0; c < 4; ++c) {
    short4_t o;
#pragma unroll
    for (int e = 0; e < 4; ++e) o[e] = (short)f2b(p[c][e] * inv);
    *reinterpret_cast<short4_t*>(P + (size_t)row * 1024 + c * 256 + lane * 4) = o;
  }
}

// ---------------------------------------------------------------------------
// 128x128-tile GEMM core. K=1024, BK=64, 512 thr = 8 waves (2m x 4n).
// 4 rotating LDS buffers (depth-2 prefetch, counted vmcnt(8), single
// s_barrier per K-step; slot reuse distance 4 >= 2 barriers -> race-free).
// XOR swizzle: LDS row = 128B = exactly 32 banks, so 16 lanes reading 16
// rows at one 16B slot would be 16-way conflicted; store chunk cb of row r
// from global col (cb^(r&7)) (linear LDS dest for gload_lds) and read slot
// (cs^(ra&7)) -> rows spread over 8 slots, 2-way residual = free.
// acc[i][j]: i = 4 m-frags (row wm*64+i*16), j = 2 n-frags (col wn*32+j*16).
// ---------------------------------------------------------------------------
__device__ __forceinline__ void gemm128_loop(
    const ushort_t* __restrict__ A0, const ushort_t* __restrict__ B0,
    ushort_t* sA, ushort_t* sB, floatx4 (&acc)[4][2])
{
  const int t = threadIdx.x;
  const int lane = t & 63, wave = t >> 6;
  const int wm = wave & 1, wn = wave >> 1;
  const int l15 = lane & 15, lk = lane >> 4;

#define STG(kt, buf)                                                        \
  {                                                                         \
    const int k0 = (kt) << 6;                                               \
    _Pragma("unroll")                                                       \
    for (int cc = 0; cc < 2; ++cc) {                                        \
      int c = t + (cc << 9);                                                \
      int r = c >> 3, cb = c & 7;                                           \
      int sc = k0 + ((cb ^ (r & 7)) << 3);                                  \
      gload16(A0 + (size_t)r * 1024 + sc, (char*)sA + (buf) * 16384 + c * 16); \
      gload16(B0 + (size_t)r * 1024 + sc, (char*)sB + (buf) * 16384 + c * 16); \
    }                                                                       \
  }

  STG(0, 0);
  STG(1, 1);
  for (int kt = 0; kt < 16; ++kt) {
    if (kt < 14) {
      STG(kt + 2, (kt + 2) & 3);
      asm volatile("s_waitcnt vmcnt(8)" ::: "memory");
    } else if (kt == 14) {
      asm volatile("s_waitcnt vmcnt(4)" ::: "memory");
    } else {
      asm volatile("s_waitcnt vmcnt(0)" ::: "memory");
    }
    __builtin_amdgcn_s_barrier();
    const char* bA = (const char*)sA + (kt & 3) * 16384;
    const char* bB = (const char*)sB + (kt & 3) * 16384;
#pragma unroll
    for (int kk = 0; kk < 2; ++kk) {
      const int cs = (kk << 2) + lk;
      short8 af[4], bf[2];
#pragma unroll
      for (int i = 0; i < 4; ++i) {
        int ra = (wm << 6) + (i << 4) + l15;
        af[i] = *reinterpret_cast<const short8*>(
            bA + ra * 128 + ((cs ^ (ra & 7)) << 4));
      }
#pragma unroll
      for (int j = 0; j < 2; ++j) {
        int rb = (wn << 5) + (j << 4) + l15;
        bf[j] = *reinterpret_cast<const short8*>(
            bB + rb * 128 + ((cs ^ (rb & 7)) << 4));
      }
      __builtin_amdgcn_s_setprio(1);
#pragma unroll
      for (int i = 0; i < 4; ++i)
#pragma unroll
        for (int j = 0; j < 2; ++j)
          acc[i][j] = mfma16(af[i], bf[j], acc[i][j]);
      __builtin_amdgcn_s_setprio(0);
    }
  }
#undef STG
}

// bijective XCD swizzle for 256-block grids (256 % 8 == 0)
__device__ __forceinline__ int xcd_swz(int bid) {
  return ((bid & 7) << 5) | (bid >> 3);
}

// ---------------------------------------------------------------------------
// GEMM 1: Yt[h*256 + b*64 + d][s] = sum_k W_in[h*64+d][k] * x[b*1024+s][k]
// M=1024 (8 m-tiles), N=4096 (32 n-tiles). grid = 256.
// ---------------------------------------------------------------------------
__global__ __launch_bounds__(512) void k_gemm_xw(
    const ushort_t* __restrict__ W, const ushort_t* __restrict__ X,
    ushort_t* __restrict__ Yt)
{
  __shared__ ushort_t sA[4 * 128 * 64];
  __shared__ ushort_t sB[4 * 128 * 64];
  const int lg = xcd_swz(blockIdx.x);
  const int m0 = (lg & 7) << 7, n0 = (lg >> 3) << 7;
  floatx4 acc[4][2] = {};
  gemm128_loop(W + (size_t)m0 * 1024, X + (size_t)n0 * 1024, sA, sB, acc);

  const int lane = threadIdx.x & 63, wave = threadIdx.x >> 6;
  const int wm = wave & 1, wn = wave >> 1;
  const int l15 = lane & 15, lk = lane >> 4;
#pragma unroll
  for (int i = 0; i < 4; ++i)
#pragma unroll
    for (int j = 0; j < 2; ++j)
#pragma unroll
      for (int rr = 0; rr < 4; ++rr) {
        int wrow = m0 + (wm << 6) + (i << 4) + (lk << 2) + rr;  // h*64+d
        int col  = n0 + (wn << 5) + (j << 4) + l15;             // b*1024+s
        int h = wrow >> 6, d = wrow & 63;
        int b = col >> 10, s = col & 1023;
        Yt[(((size_t)((h << 2) + b) << 6) + d) * 1024 + s] = f2b(acc[i][j][rr]);
      }
}

// ---------------------------------------------------------------------------
// GEMM 2 (PV): O[b][s][h*64+d] = sum_j P[h][s][j]*Yt[h][b*64+d][j] + R[h][s][d]
// Per h: M=1024 (8 m-tiles), N=256 (2 n-tiles). grid = 16*16 = 256.
// ---------------------------------------------------------------------------
__global__ __launch_bounds__(512) void k_head_pv(
    const ushort_t* __restrict__ P, const ushort_t* __restrict__ Yt,
    const float* __restrict__ R, ushort_t* __restrict__ O)
{
  __shared__ ushort_t sA[4 * 128 * 64];
  __shared__ ushort_t sB[4 * 128 * 64];
  const int lg = xcd_swz(blockIdx.x);
  const int h = lg >> 4, rem = lg & 15;
  const int m0 = (rem >> 1) << 7, n0 = (rem & 1) << 7;
  floatx4 acc[4][2] = {};
  gemm128_loop(P + ((size_t)h << 20) + (size_t)m0 * 1024,
               Yt + ((size_t)h << 18) + (size_t)n0 * 1024, sA, sB, acc);

  const int lane = threadIdx.x & 63, wave = threadIdx.x >> 6;
  const int wm = wave & 1, wn = wave >> 1;
  const int l15 = lane & 15, lk = lane >> 4;
#pragma unroll
  for (int i = 0; i < 4; ++i)
#pragma unroll
    for (int j = 0; j < 2; ++j)
#pragma unroll
      for (int rr = 0; rr < 4; ++rr) {
        int sr = m0 + (wm << 6) + (i << 4) + (lk << 2) + rr;
        int c  = n0 + (wn << 5) + (j << 4) + l15;               // b*64+d
        int b = c >> 6, d = c & 63;
        float val = acc[i][j][rr] + R[(((size_t)h << 10) + sr) * 64 + d];
        O[((size_t)b << 20) + ((size_t)sr << 10) + (h << 6) + d] = f2b(val);
      }
}

// ---------------------------------------------------------------------------
// GEMM 3: out[m][n] = sum_k O[m][k] * W_out[n][k]  (f32 out).
// M=4096 (32 m-tiles), N=1024 (8 n-tiles). grid = 256.
// ---------------------------------------------------------------------------
__global__ __launch_bounds__(512) void k_gemm_out(
    const ushort_t* __restrict__ A, const ushort_t* __restrict__ B,
    float* __restrict__ C)
{
  __shared__ ushort_t sA[4 * 128 * 64];
  __shared__ ushort_t sB[4 * 128 * 64];
  const int lg = xcd_swz(blockIdx.x);
  const int m0 = (lg >> 3) << 7, n0 = (lg & 7) << 7;
  floatx4 acc[4][2] = {};
  gemm128_loop(A + (size_t)m0 * 1024, B + (size_t)n0 * 1024, sA, sB, acc);

  const int lane = threadIdx.x & 63, wave = threadIdx.x >> 6;
  const int wm = wave & 1, wn = wave >> 1;
  const int l15 = lane & 15, lk = lane >> 4;
#pragma unroll
  for (int i = 0; i < 4; ++i)
#pragma unroll
    for (int j = 0; j < 2; ++j)
#pragma unroll
      for (int rr = 0; rr < 4; ++rr) {
        int rowg = m0 + (wm << 6) + (i << 4) + (lk << 2) + rr;
        int colg = n0 + (wn << 5) + (j << 4) + l15;
        C[(size_t)rowg * 1024 + colg] = acc[i][j][rr];
      }
}

// ---------------------------------------------------------------------------
extern "C" void kernel_launch(void* const* d_in, const int* in_sizes, int n_in,
                              void* d_out, int out_size, void* d_ws, size_t ws_size,
                              hipStream_t stream)
{
  const float* x     = (const float*)d_in[0];
  const float* W_in  = (const float*)d_in[1];
  const float* W_out = (const float*)d_in[2];
  const float* attn  = (const float*)d_in[3];
  const float* relv  = (const float*)d_in[4];
  float* out = (float*)d_out;

  char* ws = (char*)d_ws;
  ushort_t* xb  = (ushort_t*)(ws);                //  8 MB
  ushort_t* Wib = (ushort_t*)(ws + (8u << 20));   //  2 MB
  ushort_t* Wob = (ushort_t*)(ws + (10u << 20));  //  2 MB
  ushort_t* P   = (ushort_t*)(ws + (12u << 20));  // 32 MB
  float*    R   = (float*)   (ws + (44u << 20));  //  4 MB
  ushort_t* Yt  = (ushort_t*)(ws + (48u << 20));  //  8 MB  [h*256+b*64+d][s]
  ushort_t* O   = (ushort_t*)(ws + (56u << 20));  //  8 MB  [b][s][h*64+d]

  k_f2b_all<<<3072, 256, 0, stream>>>(x, W_in, W_out, xb, Wib, Wob);
  k_softmax_rel<<<4096, 256, 0, stream>>>(attn, relv, P, R);
  k_gemm_xw<<<256, 512, 0, stream>>>(Wib, xb, Yt);
  k_head_pv<<<256, 512, 0, stream>>>(P, Yt, R, O);
  k_gemm_out<<<256, 512, 0, stream>>>(O, Wob, out);
}

// Round 9
// 65.432 us; speedup vs baseline: 1.9108x; 1.0227x over previous
//
#include <hip/hip_runtime.h>

typedef unsigned short ushort_t;
typedef __attribute__((ext_vector_type(4))) short short4_t;
typedef __attribute__((ext_vector_type(8))) short short8;
typedef __attribute__((ext_vector_type(4))) float floatx4;
typedef __attribute__((ext_vector_type(8))) __bf16 bf16x8;

__device__ __forceinline__ ushort_t f2b(float f) {
  union { float f; unsigned int i; } t; t.f = f;
  unsigned int u = t.i;
  return (ushort_t)((u + 0x7fffu + ((u >> 16) & 1u)) >> 16);  // RNE
}

__device__ __forceinline__ floatx4 mfma16(short8 a, short8 b, floatx4 c) {
  return __builtin_amdgcn_mfma_f32_16x16x32_bf16(
      __builtin_bit_cast(bf16x8, a), __builtin_bit_cast(bf16x8, b), c, 0, 0, 0);
}

__device__ __forceinline__ void gload16(const void* g, void* l) {
  __builtin_amdgcn_global_load_lds(
      (const __attribute__((address_space(1))) void*)g,
      (__attribute__((address_space(3))) void*)l, 16, 0, 0);
}

// ---------------------------------------------------------------------------
// f32 -> bf16 for x (4M), W_in (1M), W_out (1M). grid = 3072.
// ---------------------------------------------------------------------------
__global__ __launch_bounds__(256) void k_f2b_all(
    const float* __restrict__ x, const float* __restrict__ Wi,
    const float* __restrict__ Wo, ushort_t* __restrict__ xb,
    ushort_t* __restrict__ Wib, ushort_t* __restrict__ Wob)
{
  const float* in; ushort_t* out; int i;
  if (blockIdx.x < 2048)      { in = x;  out = xb;  i = (blockIdx.x * 256 + threadIdx.x) * 8; }
  else if (blockIdx.x < 2560) { in = Wi; out = Wib; i = ((blockIdx.x - 2048) * 256 + threadIdx.x) * 8; }
  else                        { in = Wo; out = Wob; i = ((blockIdx.x - 2560) * 256 + threadIdx.x) * 8; }
  float4 a = *reinterpret_cast<const float4*>(in + i);
  float4 b = *reinterpret_cast<const float4*>(in + i + 4);
  short8 o;
  o[0] = (short)f2b(a.x); o[1] = (short)f2b(a.y);
  o[2] = (short)f2b(a.z); o[3] = (short)f2b(a.w);
  o[4] = (short)f2b(b.x); o[5] = (short)f2b(b.y);
  o[6] = (short)f2b(b.z); o[7] = (short)f2b(b.w);
  *reinterpret_cast<short8*>(out + i) = o;
}

// ---------------------------------------------------------------------------
// STG macro shared by both GEMM cores: stage K-tile kt (128 rows x 64 cols of
// A and B, bf16) into LDS slot `buf`. Source chunk pre-XOR-swizzled
// (cb^(r&7)) to pair with the XOR on the ds_read side (rule 21).
// ---------------------------------------------------------------------------
#define STG(kt, buf, SLOTSZ)                                                \
  {                                                                         \
    const int k0 = (kt) << 6;                                               \
    _Pragma("unroll")                                                       \
    for (int cc = 0; cc < 2; ++cc) {                                        \
      int c = threadIdx.x + (cc << 9);                                      \
      int r = c >> 3, cb = c & 7;                                           \
      int sc = k0 + ((cb ^ (r & 7)) << 3);                                  \
      gload16(A0 + (size_t)r * 1024 + sc, (char*)sA + (buf) * SLOTSZ + c * 16); \
      gload16(B0 + (size_t)r * 1024 + sc, (char*)sB + (buf) * SLOTSZ + c * 16); \
    }                                                                       \
  }

// MFMA compute for one K-step from LDS slots bA/bB (identical in both cores)
#define KSTEP_COMPUTE(bA, bB)                                               \
  _Pragma("unroll")                                                         \
  for (int kk = 0; kk < 2; ++kk) {                                          \
    const int cs = (kk << 2) + lk;                                          \
    short8 af[4], bf[2];                                                    \
    _Pragma("unroll")                                                       \
    for (int i = 0; i < 4; ++i) {                                           \
      int ra = (wm << 6) + (i << 4) + l15;                                  \
      af[i] = *reinterpret_cast<const short8*>(                             \
          (bA) + ra * 128 + ((cs ^ (ra & 7)) << 4));                        \
    }                                                                       \
    _Pragma("unroll")                                                       \
    for (int j = 0; j < 2; ++j) {                                           \
      int rb = (wn << 5) + (j << 4) + l15;                                  \
      bf[j] = *reinterpret_cast<const short8*>(                             \
          (bB) + rb * 128 + ((cs ^ (rb & 7)) << 4));                        \
    }                                                                       \
    __builtin_amdgcn_s_setprio(1);                                          \
    _Pragma("unroll")                                                       \
    for (int i = 0; i < 4; ++i)                                             \
      _Pragma("unroll")                                                     \
      for (int j = 0; j < 2; ++j)                                           \
        acc[i][j] = mfma16(af[i], bf[j], acc[i][j]);                        \
    __builtin_amdgcn_s_setprio(0);                                          \
  }

// ---------------------------------------------------------------------------
// 4-slot core (VERIFIED round 7): depth-2 prefetch, counted vmcnt(8), single
// raw s_barrier per K-step. Race-safe: slot reuse distance = 4 K-steps >= 2
// barriers between last read and overwrite. 128KB LDS -> 1 block/CU.
// ---------------------------------------------------------------------------
__device__ __forceinline__ void gemm128_loop4(
    const ushort_t* __restrict__ A0, const ushort_t* __restrict__ B0,
    ushort_t* sA, ushort_t* sB, floatx4 (&acc)[4][2])
{
  const int lane = threadIdx.x & 63, wave = threadIdx.x >> 6;
  const int wm = wave & 1, wn = wave >> 1;
  const int l15 = lane & 15, lk = lane >> 4;

  STG(0, 0, 16384);
  STG(1, 1, 16384);
  for (int kt = 0; kt < 16; ++kt) {
    if (kt < 14) {
      STG(kt + 2, (kt + 2) & 3, 16384);
      asm volatile("s_waitcnt vmcnt(8)" ::: "memory");
    } else if (kt == 14) {
      asm volatile("s_waitcnt vmcnt(4)" ::: "memory");
    } else {
      asm volatile("s_waitcnt vmcnt(0)" ::: "memory");
    }
    __builtin_amdgcn_s_barrier();
    const char* bA = (const char*)sA + (kt & 3) * 16384;
    const char* bB = (const char*)sB + (kt & 3) * 16384;
    KSTEP_COMPUTE(bA, bB);
  }
}

// ---------------------------------------------------------------------------
// 2-slot 2-phase core (guide T3 minimum recipe): STG(next) early, compute,
// __syncthreads() (= vmcnt(0)+lgkmcnt(0)+s_barrier). Race-safe: every wave's
// ds_reads of the buffer are drained (lgkmcnt) before it crosses the barrier
// that precedes the overwriting STG. 64KB LDS -> 2 blocks/CU.
// ---------------------------------------------------------------------------
__device__ __forceinline__ void gemm128_loop2(
    const ushort_t* __restrict__ A0, const ushort_t* __restrict__ B0,
    ushort_t* sA, ushort_t* sB, floatx4 (&acc)[4][2])
{
  const int lane = threadIdx.x & 63, wave = threadIdx.x >> 6;
  const int wm = wave & 1, wn = wave >> 1;
  const int l15 = lane & 15, lk = lane >> 4;

  STG(0, 0, 16384);
  for (int kt = 0; kt < 16; ++kt) {
    __syncthreads();                       // buf[kt&1] ready; prev reads drained
    if (kt < 15) STG(kt + 1, (kt + 1) & 1, 16384);
    const char* bA = (const char*)sA + (kt & 1) * 16384;
    const char* bB = (const char*)sB + (kt & 1) * 16384;
    KSTEP_COMPUTE(bA, bB);
  }
}

// bijective XCD swizzle for 256-block grids (256 % 8 == 0)
__device__ __forceinline__ int xcd_swz(int bid) {
  return ((bid & 7) << 5) | (bid >> 3);
}

// ---------------------------------------------------------------------------
// FUSED dispatch: blocks 0..255 = GEMM1 (2-phase 64KB core),
// blocks 256..2303 = softmax+rel (8 rows/block). Independent; 2 blocks/CU.
// ---------------------------------------------------------------------------
__global__ __launch_bounds__(512) void k_fused_sm_xw(
    const float* __restrict__ S, const float* __restrict__ relv,
    ushort_t* __restrict__ P, float* __restrict__ R,
    const ushort_t* __restrict__ W, const ushort_t* __restrict__ X,
    ushort_t* __restrict__ Yt)
{
  __shared__ __align__(16) char smem[65536];

  if (blockIdx.x < 256) {
    // GEMM 1: Yt[h*256 + b*64 + d][s] = sum_k W_in[h*64+d][k]*x[b*1024+s][k]
    ushort_t* sA = (ushort_t*)smem;
    ushort_t* sB = (ushort_t*)(smem + 32768);
    const int lg = xcd_swz(blockIdx.x);
    const int m0 = (lg & 7) << 7, n0 = (lg >> 3) << 7;
    const ushort_t* A0 = W + (size_t)m0 * 1024;
    const ushort_t* B0 = X + (size_t)n0 * 1024;
    floatx4 acc[4][2] = {};
    gemm128_loop2(A0, B0, sA, sB, acc);

    const int lane = threadIdx.x & 63, wave = threadIdx.x >> 6;
    const int wm = wave & 1, wn = wave >> 1;
    const int l15 = lane & 15, lk = lane >> 4;
#pragma unroll
    for (int i = 0; i < 4; ++i)
#pragma unroll
      for (int j = 0; j < 2; ++j)
#pragma unroll
        for (int rr = 0; rr < 4; ++rr) {
          int wrow = m0 + (wm << 6) + (i << 4) + (lk << 2) + rr;  // h*64+d
          int col  = n0 + (wn << 5) + (j << 4) + l15;             // b*1024+s
          int h = wrow >> 6, d = wrow & 63;
          int b = col >> 10, s = col & 1023;
          Yt[(((size_t)((h << 2) + b) << 6) + d) * 1024 + s] = f2b(acc[i][j][rr]);
        }
    return;
  }

  // ---- softmax + rel buckets: one wave per (h,s) row, 8 waves/block ----
  float (*mid)[16] = (float (*)[16])smem;
  const int wave = threadIdx.x >> 6, lane = threadIdx.x & 63;
  const int row = (blockIdx.x - 256) * 8 + wave;   // h*1024 + s
  const int s = row & 1023;
  const float* src = S + (size_t)row * 1024;

  float v[4][4];
#pragma unroll
  for (int c = 0; c < 4; ++c) {
    float4 raw = *reinterpret_cast<const float4*>(src + c * 256 + lane * 4);
    v[c][0] = raw.x; v[c][1] = raw.y; v[c][2] = raw.z; v[c][3] = raw.w;
  }
  float m = -1e30f;
#pragma unroll
  for (int c = 0; c < 4; ++c)
#pragma unroll
    for (int e = 0; e < 4; ++e) m = fmaxf(m, v[c][e]);
#pragma unroll
  for (int d = 32; d; d >>= 1) m = fmaxf(m, __shfl_xor(m, d));

  float p[4][4];
  float tot = 0.f, sA = 0.f, sB = 0.f;
#pragma unroll
  for (int c = 0; c < 4; ++c) {
#pragma unroll
    for (int e = 0; e < 4; ++e) {
      int j = c * 256 + lane * 4 + e;
      float pe = __expf(v[c][e] - m);
      p[c][e] = pe;
      tot += pe;
      sA += (j <= s - 8) ? pe : 0.f;
      sB += (j >= s + 8) ? pe : 0.f;
    }
  }
#pragma unroll
  for (int d = 32; d; d >>= 1) {
    tot += __shfl_xor(tot, d);
    sA  += __shfl_xor(sA, d);
    sB  += __shfl_xor(sB, d);
  }
  const float inv = 1.0f / tot;

  if (lane < 16) mid[wave][lane] = 0.f;
  __syncthreads();
#pragma unroll
  for (int c = 0; c < 4; ++c) {
#pragma unroll
    for (int e = 0; e < 4; ++e) {
      int j = c * 256 + lane * 4 + e;
      int tt = j - (s - 7);
      if (tt >= 0 && tt < 15) mid[wave][tt] = p[c][e];
    }
  }
  __syncthreads();

  float acc = sA * relv[lane] + sB * relv[16 * 64 + lane];
#pragma unroll
  for (int tt = 0; tt < 15; ++tt)
    acc += mid[wave][tt] * relv[(1 + tt) * 64 + lane];
  R[(size_t)row * 64 + lane] = acc * inv;

#pragma unroll
  for (int c = 0; c < 4; ++c) {
    short4_t o;
#pragma unroll
    for (int e = 0; e < 4; ++e) o[e] = (short)f2b(p[c][e] * inv);
    *reinterpret_cast<short4_t*>(P + (size_t)row * 1024 + c * 256 + lane * 4) = o;
  }
}

// ---------------------------------------------------------------------------
// GEMM 2 (PV): O[b][s][h*64+d] = sum_j P[h][s][j]*Yt[h][b*64+d][j] + R[h][s][d]
// Per h: M=1024 (8 m-tiles), N=256 (2 n-tiles). grid = 256. (4-slot core)
// ---------------------------------------------------------------------------
__global__ __launch_bounds__(512) void k_head_pv(
    const ushort_t* __restrict__ P, const ushort_t* __restrict__ Yt,
    const float* __restrict__ R, ushort_t* __restrict__ O)
{
  __shared__ ushort_t sA[4 * 128 * 64];
  __shared__ ushort_t sB[4 * 128 * 64];
  const int lg = xcd_swz(blockIdx.x);
  const int h = lg >> 4, rem = lg & 15;
  const int m0 = (rem >> 1) << 7, n0 = (rem & 1) << 7;
  floatx4 acc[4][2] = {};
  gemm128_loop4(P + ((size_t)h << 20) + (size_t)m0 * 1024,
                Yt + ((size_t)h << 18) + (size_t)n0 * 1024, sA, sB, acc);

  const int lane = threadIdx.x & 63, wave = threadIdx.x >> 6;
  const int wm = wave & 1, wn = wave >> 1;
  const int l15 = lane & 15, lk = lane >> 4;
#pragma unroll
  for (int i = 0; i < 4; ++i)
#pragma unroll
    for (int j = 0; j < 2; ++j)
#pragma unroll
      for (int rr = 0; rr < 4; ++rr) {
        int sr = m0 + (wm << 6) + (i << 4) + (lk << 2) + rr;
        int c  = n0 + (wn << 5) + (j << 4) + l15;               // b*64+d
        int b = c >> 6, d = c & 63;
        float val = acc[i][j][rr] + R[(((size_t)h << 10) + sr) * 64 + d];
        O[((size_t)b << 20) + ((size_t)sr << 10) + (h << 6) + d] = f2b(val);
      }
}

// ---------------------------------------------------------------------------
// GEMM 3: out[m][n] = sum_k O[m][k] * W_out[n][k]  (f32 out). grid = 256.
// (4-slot core)
// ---------------------------------------------------------------------------
__global__ __launch_bounds__(512) void k_gemm_out(
    const ushort_t* __restrict__ A, const ushort_t* __restrict__ B,
    float* __restrict__ C)
{
  __shared__ ushort_t sA[4 * 128 * 64];
  __shared__ ushort_t sB[4 * 128 * 64];
  const int lg = xcd_swz(blockIdx.x);
  const int m0 = (lg >> 3) << 7, n0 = (lg & 7) << 7;
  floatx4 acc[4][2] = {};
  gemm128_loop4(A + (size_t)m0 * 1024, B + (size_t)n0 * 1024, sA, sB, acc);

  const int lane = threadIdx.x & 63, wave = threadIdx.x >> 6;
  const int wm = wave & 1, wn = wave >> 1;
  const int l15 = lane & 15, lk = lane >> 4;
#pragma unroll
  for (int i = 0; i < 4; ++i)
#pragma unroll
    for (int j = 0; j < 2; ++j)
#pragma unroll
      for (int rr = 0; rr < 4; ++rr) {
        int rowg = m0 + (wm << 6) + (i << 4) + (lk << 2) + rr;
        int colg = n0 + (wn << 5) + (j << 4) + l15;
        C[(size_t)rowg * 1024 + colg] = acc[i][j][rr];
      }
}

// ---------------------------------------------------------------------------
extern "C" void kernel_launch(void* const* d_in, const int* in_sizes, int n_in,
                              void* d_out, int out_size, void* d_ws, size_t ws_size,
                              hipStream_t stream)
{
  const float* x     = (const float*)d_in[0];
  const float* W_in  = (const float*)d_in[1];
  const float* W_out = (const float*)d_in[2];
  const float* attn  = (const float*)d_in[3];
  const float* relv  = (const float*)d_in[4];
  float* out = (float*)d_out;

  char* ws = (char*)d_ws;
  ushort_t* xb  = (ushort_t*)(ws);                //  8 MB
  ushort_t* Wib = (ushort_t*)(ws + (8u << 20));   //  2 MB
  ushort_t* Wob = (ushort_t*)(ws + (10u << 20));  //  2 MB
  ushort_t* P   = (ushort_t*)(ws + (12u << 20));  // 32 MB
  float*    R   = (float*)   (ws + (44u << 20));  //  4 MB
  ushort_t* Yt  = (ushort_t*)(ws + (48u << 20));  //  8 MB  [h*256+b*64+d][s]
  ushort_t* O   = (ushort_t*)(ws + (56u << 20));  //  8 MB  [b][s][h*64+d]

  k_f2b_all<<<3072, 256, 0, stream>>>(x, W_in, W_out, xb, Wib, Wob);
  k_fused_sm_xw<<<2304, 512, 0, stream>>>(attn, relv, P, R, Wib, xb, Yt);
  k_head_pv<<<256, 512, 0, stream>>>(P, Yt, R, O);
  k_gemm_out<<<256, 512, 0, stream>>>(O, Wob, out);
}

// Round 10
// 64.967 us; speedup vs baseline: 1.9245x; 1.0072x over previous
//
#include <hip/hip_runtime.h>

typedef unsigned short ushort_t;
typedef __attribute__((ext_vector_type(4))) short short4_t;
typedef __attribute__((ext_vector_type(8))) short short8;
typedef __attribute__((ext_vector_type(4))) float floatx4;
typedef __attribute__((ext_vector_type(8))) __bf16 bf16x8;

__device__ __forceinline__ ushort_t f2b(float f) {
  union { float f; unsigned int i; } t; t.f = f;
  unsigned int u = t.i;
  return (ushort_t)((u + 0x7fffu + ((u >> 16) & 1u)) >> 16);  // RNE
}

__device__ __forceinline__ floatx4 mfma16(short8 a, short8 b, floatx4 c) {
  return __builtin_amdgcn_mfma_f32_16x16x32_bf16(
      __builtin_bit_cast(bf16x8, a), __builtin_bit_cast(bf16x8, b), c, 0, 0, 0);
}

__device__ __forceinline__ void gload16(const void* g, void* l) {
  __builtin_amdgcn_global_load_lds(
      (const __attribute__((address_space(1))) void*)g,
      (__attribute__((address_space(3))) void*)l, 16, 0, 0);
}

// ---------------------------------------------------------------------------
// FUSED memory-bound dispatch (all 256-thread, tiny-LDS blocks):
//   blocks 0..3071    : f2b conversion of x / W_in / W_out
//   blocks 3072..7167 : softmax+rel rows (one wave per (h,s) row)
// Independent works; both HBM-bound -> share the BW pipe at high occupancy.
// ---------------------------------------------------------------------------
__global__ __launch_bounds__(256) void k_sm_f2b(
    const float* __restrict__ S, const float* __restrict__ relv,
    ushort_t* __restrict__ P, float* __restrict__ R,
    const float* __restrict__ x, const float* __restrict__ Wi,
    const float* __restrict__ Wo, ushort_t* __restrict__ xb,
    ushort_t* __restrict__ Wib, ushort_t* __restrict__ Wob)
{
  __shared__ float mid[4][16];

  if (blockIdx.x < 3072) {
    const float* in; ushort_t* out; int i;
    if (blockIdx.x < 2048)      { in = x;  out = xb;  i = (blockIdx.x * 256 + threadIdx.x) * 8; }
    else if (blockIdx.x < 2560) { in = Wi; out = Wib; i = ((blockIdx.x - 2048) * 256 + threadIdx.x) * 8; }
    else                        { in = Wo; out = Wob; i = ((blockIdx.x - 2560) * 256 + threadIdx.x) * 8; }
    float4 a = *reinterpret_cast<const float4*>(in + i);
    float4 b = *reinterpret_cast<const float4*>(in + i + 4);
    short8 o;
    o[0] = (short)f2b(a.x); o[1] = (short)f2b(a.y);
    o[2] = (short)f2b(a.z); o[3] = (short)f2b(a.w);
    o[4] = (short)f2b(b.x); o[5] = (short)f2b(b.y);
    o[6] = (short)f2b(b.z); o[7] = (short)f2b(b.w);
    *reinterpret_cast<short8*>(out + i) = o;
    return;
  }

  // ---- softmax + rel buckets (verified round 2-4) ----
  const int wave = threadIdx.x >> 6, lane = threadIdx.x & 63;
  const int row = (blockIdx.x - 3072) * 4 + wave;   // h*1024 + s
  const int s = row & 1023;
  const float* src = S + (size_t)row * 1024;

  float v[4][4];
#pragma unroll
  for (int c = 0; c < 4; ++c) {
    float4 raw = *reinterpret_cast<const float4*>(src + c * 256 + lane * 4);
    v[c][0] = raw.x; v[c][1] = raw.y; v[c][2] = raw.z; v[c][3] = raw.w;
  }
  float m = -1e30f;
#pragma unroll
  for (int c = 0; c < 4; ++c)
#pragma unroll
    for (int e = 0; e < 4; ++e) m = fmaxf(m, v[c][e]);
#pragma unroll
  for (int d = 32; d; d >>= 1) m = fmaxf(m, __shfl_xor(m, d));

  float p[4][4];
  float tot = 0.f, sA = 0.f, sB = 0.f;
#pragma unroll
  for (int c = 0; c < 4; ++c) {
#pragma unroll
    for (int e = 0; e < 4; ++e) {
      int j = c * 256 + lane * 4 + e;
      float pe = __expf(v[c][e] - m);
      p[c][e] = pe;
      tot += pe;
      sA += (j <= s - 8) ? pe : 0.f;
      sB += (j >= s + 8) ? pe : 0.f;
    }
  }
#pragma unroll
  for (int d = 32; d; d >>= 1) {
    tot += __shfl_xor(tot, d);
    sA  += __shfl_xor(sA, d);
    sB  += __shfl_xor(sB, d);
  }
  const float inv = 1.0f / tot;

  if (lane < 16) mid[wave][lane] = 0.f;
  __syncthreads();
#pragma unroll
  for (int c = 0; c < 4; ++c) {
#pragma unroll
    for (int e = 0; e < 4; ++e) {
      int j = c * 256 + lane * 4 + e;
      int tt = j - (s - 7);
      if (tt >= 0 && tt < 15) mid[wave][tt] = p[c][e];
    }
  }
  __syncthreads();

  float acc = sA * relv[lane] + sB * relv[16 * 64 + lane];
#pragma unroll
  for (int tt = 0; tt < 15; ++tt)
    acc += mid[wave][tt] * relv[(1 + tt) * 64 + lane];
  R[(size_t)row * 64 + lane] = acc * inv;

#pragma unroll
  for (int c = 0; c < 4; ++c) {
    short4_t o;
#pragma unroll
    for (int e = 0; e < 4; ++e) o[e] = (short)f2b(p[c][e] * inv);
    *reinterpret_cast<short4_t*>(P + (size_t)row * 1024 + c * 256 + lane * 4) = o;
  }
}

// ---------------------------------------------------------------------------
// STG: stage K-tile kt (128 rows x 64 cols of A and B, bf16) into LDS slot.
// Source chunk pre-XOR-swizzled (cb^(r&7)) to pair with the read-side XOR.
// ---------------------------------------------------------------------------
#define STG(kt, buf)                                                        \
  {                                                                         \
    const int k0 = (kt) << 6;                                               \
    _Pragma("unroll")                                                       \
    for (int cc = 0; cc < 2; ++cc) {                                        \
      int c = threadIdx.x + (cc << 9);                                      \
      int r = c >> 3, cb = c & 7;                                           \
      int sc = k0 + ((cb ^ (r & 7)) << 3);                                  \
      gload16(A0 + (size_t)r * 1024 + sc, (char*)sA + (buf) * 16384 + c * 16); \
      gload16(B0 + (size_t)r * 1024 + sc, (char*)sB + (buf) * 16384 + c * 16); \
    }                                                                       \
  }

#define KSTEP_COMPUTE(bA, bB)                                               \
  _Pragma("unroll")                                                         \
  for (int kk = 0; kk < 2; ++kk) {                                          \
    const int cs = (kk << 2) + lk;                                          \
    short8 af[4], bf[2];                                                    \
    _Pragma("unroll")                                                       \
    for (int i = 0; i < 4; ++i) {                                           \
      int ra = (wm << 6) + (i << 4) + l15;                                  \
      af[i] = *reinterpret_cast<const short8*>(                             \
          (bA) + ra * 128 + ((cs ^ (ra & 7)) << 4));                        \
    }                                                                       \
    _Pragma("unroll")                                                       \
    for (int j = 0; j < 2; ++j) {                                           \
      int rb = (wn << 5) + (j << 4) + l15;                                  \
      bf[j] = *reinterpret_cast<const short8*>(                             \
          (bB) + rb * 128 + ((cs ^ (rb & 7)) << 4));                        \
    }                                                                       \
    __builtin_amdgcn_s_setprio(1);                                          \
    _Pragma("unroll")                                                       \
    for (int i = 0; i < 4; ++i)                                             \
      _Pragma("unroll")                                                     \
      for (int j = 0; j < 2; ++j)                                           \
        acc[i][j] = mfma16(af[i], bf[j], acc[i][j]);                        \
    __builtin_amdgcn_s_setprio(0);                                          \
  }

// ---------------------------------------------------------------------------
// 4-slot 128x128 GEMM core (VERIFIED round 7): depth-2 prefetch, counted
// vmcnt(8), one raw s_barrier per K-step. Slot reuse distance = 4 K-steps.
// ---------------------------------------------------------------------------
__device__ __forceinline__ void gemm128_loop4(
    const ushort_t* __restrict__ A0, const ushort_t* __restrict__ B0,
    ushort_t* sA, ushort_t* sB, floatx4 (&acc)[4][2])
{
  const int lane = threadIdx.x & 63, wave = threadIdx.x >> 6;
  const int wm = wave & 1, wn = wave >> 1;
  const int l15 = lane & 15, lk = lane >> 4;

  STG(0, 0);
  STG(1, 1);
  for (int kt = 0; kt < 16; ++kt) {
    if (kt < 14) {
      STG(kt + 2, (kt + 2) & 3);
      asm volatile("s_waitcnt vmcnt(8)" ::: "memory");
    } else if (kt == 14) {
      asm volatile("s_waitcnt vmcnt(4)" ::: "memory");
    } else {
      asm volatile("s_waitcnt vmcnt(0)" ::: "memory");
    }
    __builtin_amdgcn_s_barrier();
    const char* bA = (const char*)sA + (kt & 3) * 16384;
    const char* bB = (const char*)sB + (kt & 3) * 16384;
    KSTEP_COMPUTE(bA, bB);
  }
}

// bijective XCD swizzle for 256-block grids (256 % 8 == 0)
__device__ __forceinline__ int xcd_swz(int bid) {
  return ((bid & 7) << 5) | (bid >> 3);
}

// ---------------------------------------------------------------------------
// GEMM 1: Yt[h*256 + b*64 + d][s] = sum_k W_in[h*64+d][k] * x[b*1024+s][k]
// M=1024 (8 m-tiles), N=4096 (32 n-tiles). grid = 256.
// ---------------------------------------------------------------------------
__global__ __launch_bounds__(512) void k_gemm_xw(
    const ushort_t* __restrict__ W, const ushort_t* __restrict__ X,
    ushort_t* __restrict__ Yt)
{
  __shared__ ushort_t sA[4 * 128 * 64];
  __shared__ ushort_t sB[4 * 128 * 64];
  const int lg = xcd_swz(blockIdx.x);
  const int m0 = (lg & 7) << 7, n0 = (lg >> 3) << 7;
  const ushort_t* A0 = W + (size_t)m0 * 1024;
  const ushort_t* B0 = X + (size_t)n0 * 1024;
  floatx4 acc[4][2] = {};
  gemm128_loop4(A0, B0, sA, sB, acc);

  const int lane = threadIdx.x & 63, wave = threadIdx.x >> 6;
  const int wm = wave & 1, wn = wave >> 1;
  const int l15 = lane & 15, lk = lane >> 4;
#pragma unroll
  for (int i = 0; i < 4; ++i)
#pragma unroll
    for (int j = 0; j < 2; ++j)
#pragma unroll
      for (int rr = 0; rr < 4; ++rr) {
        int wrow = m0 + (wm << 6) + (i << 4) + (lk << 2) + rr;  // h*64+d
        int col  = n0 + (wn << 5) + (j << 4) + l15;             // b*1024+s
        int h = wrow >> 6, d = wrow & 63;
        int b = col >> 10, s = col & 1023;
        Yt[(((size_t)((h << 2) + b) << 6) + d) * 1024 + s] = f2b(acc[i][j][rr]);
      }
}

// ---------------------------------------------------------------------------
// GEMM 2 (PV): O[b][s][h*64+d] = sum_j P[h][s][j]*Yt[h][b*64+d][j] + R[h][s][d]
// Per h: M=1024 (8 m-tiles), N=256 (2 n-tiles). grid = 256.
// ---------------------------------------------------------------------------
__global__ __launch_bounds__(512) void k_head_pv(
    const ushort_t* __restrict__ P, const ushort_t* __restrict__ Yt,
    const float* __restrict__ R, ushort_t* __restrict__ O)
{
  __shared__ ushort_t sA[4 * 128 * 64];
  __shared__ ushort_t sB[4 * 128 * 64];
  const int lg = xcd_swz(blockIdx.x);
  const int h = lg >> 4, rem = lg & 15;
  const int m0 = (rem >> 1) << 7, n0 = (rem & 1) << 7;
  const ushort_t* A0 = P + ((size_t)h << 20) + (size_t)m0 * 1024;
  const ushort_t* B0 = Yt + ((size_t)h << 18) + (size_t)n0 * 1024;
  floatx4 acc[4][2] = {};
  gemm128_loop4(A0, B0, sA, sB, acc);

  const int lane = threadIdx.x & 63, wave = threadIdx.x >> 6;
  const int wm = wave & 1, wn = wave >> 1;
  const int l15 = lane & 15, lk = lane >> 4;
#pragma unroll
  for (int i = 0; i < 4; ++i)
#pragma unroll
    for (int j = 0; j < 2; ++j)
#pragma unroll
      for (int rr = 0; rr < 4; ++rr) {
        int sr = m0 + (wm << 6) + (i << 4) + (lk << 2) + rr;
        int c  = n0 + (wn << 5) + (j << 4) + l15;               // b*64+d
        int b = c >> 6, d = c & 63;
        float val = acc[i][j][rr] + R[(((size_t)h << 10) + sr) * 64 + d];
        O[((size_t)b << 20) + ((size_t)sr << 10) + (h << 6) + d] = f2b(val);
      }
}

// ---------------------------------------------------------------------------
// GEMM 3: out[m][n] = sum_k O[m][k] * W_out[n][k]  (f32 out). grid = 256.
// ---------------------------------------------------------------------------
__global__ __launch_bounds__(512) void k_gemm_out(
    const ushort_t* __restrict__ A, const ushort_t* __restrict__ B,
    float* __restrict__ C)
{
  __shared__ ushort_t sA[4 * 128 * 64];
  __shared__ ushort_t sB[4 * 128 * 64];
  const int lg = xcd_swz(blockIdx.x);
  const int m0 = (lg >> 3) << 7, n0 = (lg & 7) << 7;
  const ushort_t* A0 = A + (size_t)m0 * 1024;
  const ushort_t* B0 = B + (size_t)n0 * 1024;
  floatx4 acc[4][2] = {};
  gemm128_loop4(A0, B0, sA, sB, acc);

  const int lane = threadIdx.x & 63, wave = threadIdx.x >> 6;
  const int wm = wave & 1, wn = wave >> 1;
  const int l15 = lane & 15, lk = lane >> 4;
#pragma unroll
  for (int i = 0; i < 4; ++i)
#pragma unroll
    for (int j = 0; j < 2; ++j)
#pragma unroll
      for (int rr = 0; rr < 4; ++rr) {
        int rowg = m0 + (wm << 6) + (i << 4) + (lk << 2) + rr;
        int colg = n0 + (wn << 5) + (j << 4) + l15;
        C[(size_t)rowg * 1024 + colg] = acc[i][j][rr];
      }
}

// ---------------------------------------------------------------------------
extern "C" void kernel_launch(void* const* d_in, const int* in_sizes, int n_in,
                              void* d_out, int out_size, void* d_ws, size_t ws_size,
                              hipStream_t stream)
{
  const float* x     = (const float*)d_in[0];
  const float* W_in  = (const float*)d_in[1];
  const float* W_out = (const float*)d_in[2];
  const float* attn  = (const float*)d_in[3];
  const float* relv  = (const float*)d_in[4];
  float* out = (float*)d_out;

  char* ws = (char*)d_ws;
  ushort_t* xb  = (ushort_t*)(ws);                //  8 MB
  ushort_t* Wib = (ushort_t*)(ws + (8u << 20));   //  2 MB
  ushort_t* Wob = (ushort_t*)(ws + (10u << 20));  //  2 MB
  ushort_t* P   = (ushort_t*)(ws + (12u << 20));  // 32 MB
  float*    R   = (float*)   (ws + (44u << 20));  //  4 MB
  ushort_t* Yt  = (ushort_t*)(ws + (48u << 20));  //  8 MB  [h*256+b*64+d][s]
  ushort_t* O   = (ushort_t*)(ws + (56u << 20));  //  8 MB  [b][s][h*64+d]

  k_sm_f2b<<<7168, 256, 0, stream>>>(attn, relv, P, R, x, W_in, W_out, xb, Wib, Wob);
  k_gemm_xw<<<256, 512, 0, stream>>>(Wib, xb, Yt);
  k_head_pv<<<256, 512, 0, stream>>>(P, Yt, R, O);
  k_gemm_out<<<256, 512, 0, stream>>>(O, Wob, out);
}